// Round 2
// baseline (636.926 us; speedup 1.0000x reference)
//
#include <hip/hip_runtime.h>

#define N_VERT 35709
#define N_FACE 70789
#define NB 32
#define M3 (3*N_VERT)        // 107127
#define V4 (N_VERT*4)        // 142836  fs4 per-batch stride (floats)
#define NF4 ((N_FACE+1)*4)   // 283160  fn4 per-batch stride (incl. zero row at idx N_FACE)

// ---- workspace layout (float offsets) ----
#define WS_FS4   ((size_t)0)                      // [32][N_VERT][4]
#define WS_FN4   (WS_FS4 + (size_t)NB*V4)         // [32][N_FACE+1][4]
#define WS_CPAD  (WS_FN4 + (size_t)NB*NF4)        // [32][256]
#define WS_ROT   (WS_CPAD + (size_t)NB*256)       // [32][9]
#define WS_TRE   (WS_ROT + (size_t)NB*9)          // [32][3]
#define WS_G     (WS_TRE + (size_t)NB*3)          // [32][27]
#define WS_MEAN  (WS_G + (size_t)NB*27)           // [3] atomic sums

// ---- output layout (float offsets) ----
#define FC_OFF   ((size_t)0)
#define LM_OFF   ((size_t)NB*M3)                  // 3428064
#define FST_OFF  (LM_OFF + (size_t)NB*68*2)

// ---- SH constants ----
#define A0C0 0.88622692545275801f
#define A1C1 1.77245385090551603f
#define A2C2 2.42703239430f
#define Y6C  0.70062393935f
#define Y8C  1.21351619715f

#define CBLK 277   // ceil(N_FACE+1 coverage /256) for stage C
#define DBLK 140   // ceil(N_VERT/256) for stage D

// ======================= Stage A1: meanshape partial sums =======================
__global__ void __launch_bounds__(256) face3d_stageA1(
    const float* __restrict__ ms, float* __restrict__ ws) {
  float s0=0.f, s1=0.f, s2=0.f;
  for (int v = blockIdx.x*256 + threadIdx.x; v < N_VERT; v += gridDim.x*256) {
    s0 += ms[3*v+0]; s1 += ms[3*v+1]; s2 += ms[3*v+2];
  }
  #pragma unroll
  for (int off = 32; off > 0; off >>= 1) {
    s0 += __shfl_down(s0, off);
    s1 += __shfl_down(s1, off);
    s2 += __shfl_down(s2, off);
  }
  if ((threadIdx.x & 63) == 0) {
    atomicAdd(&ws[WS_MEAN+0], s0);
    atomicAdd(&ws[WS_MEAN+1], s1);
    atomicAdd(&ws[WS_MEAN+2], s2);
  }
}

// ======================= Stage A2: per-batch constants =======================
__global__ void __launch_bounds__(256) face3d_stageA2(
    const float* __restrict__ coeff, float* __restrict__ ws) {
  int t = threadIdx.x;
  float m0 = ws[WS_MEAN+0]*(1.0f/N_VERT);
  float m1 = ws[WS_MEAN+1]*(1.0f/N_VERT);
  float m2 = ws[WS_MEAN+2]*(1.0f/N_VERT);
  for (int idx = t; idx < NB*256; idx += 256) {
    int b = idx >> 8, k = idx & 255;
    ws[WS_CPAD + idx] = (k < 244) ? coeff[b*277 + k] : 0.0f;
  }
  for (int idx = t; idx < NB*27; idx += 256) {
    int b = idx / 27, k = idx - b*27;
    ws[WS_G + idx] = coeff[b*277 + 247 + k] + (((k % 9) == 0) ? 0.8f : 0.0f);
  }
  if (t < NB) {
    int b = t;
    float ax = coeff[b*277+244], ay = coeff[b*277+245], az = coeff[b*277+246];
    float cx=cosf(ax), sx=sinf(ax);
    float cy=cosf(ay), sy=sinf(ay);
    float cz=cosf(az), sz=sinf(az);
    float T00=cz*cy, T01=-sz, T02=cz*sy;
    float T10=sz*cy, T11=cz,  T12=sz*sy;
    float T20=-sy,   T21=0.f, T22=cy;
    float R[3][3];
    R[0][0]=T00; R[0][1]=T01*cx+T02*sx; R[0][2]=-T01*sx+T02*cx;
    R[1][0]=T10; R[1][1]=T11*cx+T12*sx; R[1][2]=-T11*sx+T12*cx;
    R[2][0]=T20; R[2][1]=T21*cx+T22*sx; R[2][2]=-T21*sx+T22*cx;
    float rot[3][3];
    #pragma unroll
    for (int c=0;c<3;c++)
      #pragma unroll
      for (int j=0;j<3;j++)
        rot[c][j] = R[j][c];
    #pragma unroll
    for (int c=0;c<3;c++)
      #pragma unroll
      for (int j=0;j<3;j++)
        ws[WS_ROT + b*9 + c*3 + j] = rot[c][j];
    #pragma unroll
    for (int j=0;j<3;j++)
      ws[WS_TRE + b*3 + j] = coeff[b*277+274+j]
        - (m0*rot[0][j] + m1*rot[1][j] + m2*rot[2][j]);
  }
}

// ======================= Stage B: GEMMs (2 rows x 8 batches / thread) =======================
template<int NK4>
__device__ __forceinline__ void phase2(const float* __restrict__ a0p,
                                       const float* __restrict__ a1p,
                                       const float4* __restrict__ B4,   // LDS, stride 64 float4/batch
                                       float* __restrict__ acc0,
                                       float* __restrict__ acc1) {
  const float4* __restrict__ p0 = (const float4*)a0p;
  const float4* __restrict__ p1 = (const float4*)a1p;
  float4 c0 = p0[0], c1 = p1[0];
  #pragma unroll 1
  for (int s = 0; s < NK4; ++s) {
    float4 a0 = c0, a1 = c1;
    if (s + 1 < NK4) { c0 = p0[s+1]; c1 = p1[s+1]; }
    #pragma unroll
    for (int b = 0; b < 8; ++b) {
      float4 w = B4[b*64 + s];
      acc0[b] = fmaf(a0.x, w.x, fmaf(a0.y, w.y, fmaf(a0.z, w.z, fmaf(a0.w, w.w, acc0[b]))));
      acc1[b] = fmaf(a1.x, w.x, fmaf(a1.y, w.y, fmaf(a1.z, w.z, fmaf(a1.w, w.w, acc1[b]))));
    }
  }
}

__global__ void __launch_bounds__(256) face3d_stageB(
    const float* __restrict__ idB, const float* __restrict__ exB,
    const float* __restrict__ texB, const float* __restrict__ meanshape,
    const float* __restrict__ meantex, const float* __restrict__ cpad,
    float* __restrict__ fs4, float* __restrict__ texOut) {
  __shared__ float4 BcV[512];   // [8 batches][64 float4]
  int t = threadIdx.x;
  int bgrp = blockIdx.x & 3;
  int rb   = blockIdx.x >> 2;
  int b0 = bgrp*8;
  {
    const float4* src = (const float4*)(cpad + b0*256);
    BcV[t]     = src[t];
    BcV[t+256] = src[t+256];
  }
  __syncthreads();
  int r0 = rb*512 + 2*t;
  if (r0 >= M3) return;
  int r1c = (r0+1 < M3) ? (r0+1) : r0;   // clamped for loads
  bool has2 = (r0+1 < M3);

  float acc0[8], acc1[8];
  #pragma unroll
  for (int b=0;b<8;b++){acc0[b]=0.f;acc1[b]=0.f;}
  phase2<20>(idB + (size_t)r0*80,  idB + (size_t)r1c*80,  BcV,      acc0, acc1);
  phase2<16>(exB + (size_t)r0*64,  exB + (size_t)r1c*64,  BcV + 20, acc0, acc1);

  {
    float ms0 = meanshape[r0], ms1 = meanshape[r1c];
    int v0 = r0/3,      c0i = r0 - 3*v0;
    int v1 = (r0+1)/3,  c1i = (r0+1) - 3*v1;
    #pragma unroll
    for (int b=0;b<8;b++) {
      size_t base = (size_t)(b0+b)*V4;
      fs4[base + (size_t)v0*4 + c0i] = acc0[b] + ms0;
      if (has2) fs4[base + (size_t)v1*4 + c1i] = acc1[b] + ms1;
    }
  }

  #pragma unroll
  for (int b=0;b<8;b++){acc0[b]=0.f;acc1[b]=0.f;}
  phase2<25>(texB + (size_t)r0*100, texB + (size_t)r1c*100, BcV + 36, acc0, acc1);
  {
    float mt0 = meantex[r0], mt1 = meantex[r1c];
    #pragma unroll
    for (int b=0;b<8;b++) {
      size_t base = FC_OFF + (size_t)(b0+b)*M3;
      texOut[base + r0] = acc0[b] + mt0;
      if (has2) texOut[base + r0 + 1] = acc1[b] + mt1;
    }
  }
}

// ======================= Stage C: face normals =======================
__global__ void __launch_bounds__(256) face3d_stageC(
    const int* __restrict__ face_buf, const float* __restrict__ fs4,
    float* __restrict__ fn4) {
  int bid = blockIdx.x;
  int b = (bid & 7) + 8*(bid / (8*CBLK));      // XCD-stable batch per phase
  int vblk = (bid >> 3) % CBLK;
  int f = vblk*256 + threadIdx.x;
  if (f > N_FACE) return;
  float* o = fn4 + (size_t)b*NF4 + (size_t)f*4;
  if (f == N_FACE) { *(float4*)o = make_float4(0.f,0.f,0.f,0.f); return; }
  const float* fs = fs4 + (size_t)b*V4;
  int i0 = face_buf[f*3+0];
  int i1 = face_buf[f*3+1];
  int i2 = face_buf[f*3+2];
  float4 p1 = *(const float4*)(fs + (size_t)i0*4);
  float4 p2 = *(const float4*)(fs + (size_t)i1*4);
  float4 p3 = *(const float4*)(fs + (size_t)i2*4);
  float e1x = p1.x-p2.x, e1y = p1.y-p2.y, e1z = p1.z-p2.z;
  float e2x = p2.x-p3.x, e2y = p2.y-p3.y, e2z = p2.z-p3.z;
  float nx = e1y*e2z - e1z*e2y;
  float ny = e1z*e2x - e1x*e2z;
  float nz = e1x*e2y - e1y*e2x;
  float inv = 1.0f / fmaxf(sqrtf(nx*nx + ny*ny + nz*nz), 1e-12f);
  *(float4*)o = make_float4(nx*inv, ny*inv, nz*inv, 0.f);
}

// ======================= Stage D: vertex normals + lighting + fst (+landmarks) =======================
__global__ void __launch_bounds__(256) face3d_stageD(
    const int* __restrict__ point_buf, const int* __restrict__ keypoints,
    const float* __restrict__ fs4, const float* __restrict__ fn4,
    const float* __restrict__ rotAll, const float* __restrict__ treAll,
    const float* __restrict__ gAll, float* __restrict__ out) {
  const int mainBlocks = NB*DBLK;
  int bid = blockIdx.x;
  if (bid < mainBlocks) {
    int b = (bid & 7) + 8*(bid / (8*DBLK));
    int v = ((bid >> 3) % DBLK)*256 + threadIdx.x;
    if (v >= N_VERT) return;
    const float* __restrict__ fn = fn4 + (size_t)b*NF4;
    int4 pb0 = *(const int4*)(point_buf + (size_t)v*8);
    int4 pb1 = *(const int4*)(point_buf + (size_t)v*8 + 4);
    float4 g0 = *(const float4*)(fn + (size_t)pb0.x*4);
    float4 g1 = *(const float4*)(fn + (size_t)pb0.y*4);
    float4 g2 = *(const float4*)(fn + (size_t)pb0.z*4);
    float4 g3 = *(const float4*)(fn + (size_t)pb0.w*4);
    float4 g4 = *(const float4*)(fn + (size_t)pb1.x*4);
    float4 g5 = *(const float4*)(fn + (size_t)pb1.y*4);
    float4 g6 = *(const float4*)(fn + (size_t)pb1.z*4);
    float4 g7 = *(const float4*)(fn + (size_t)pb1.w*4);
    float sx = ((g0.x+g1.x)+(g2.x+g3.x)) + ((g4.x+g5.x)+(g6.x+g7.x));
    float sy = ((g0.y+g1.y)+(g2.y+g3.y)) + ((g4.y+g5.y)+(g6.y+g7.y));
    float sz = ((g0.z+g1.z)+(g2.z+g3.z)) + ((g4.z+g5.z)+(g6.z+g7.z));
    float inv = 1.0f / fmaxf(sqrtf(sx*sx + sy*sy + sz*sz), 1e-12f);
    float n0 = sx*inv, n1 = sy*inv, n2 = sz*inv;
    const float* rot = rotAll + b*9;
    float r00=rot[0], r01=rot[1], r02=rot[2];
    float r10=rot[3], r11=rot[4], r12=rot[5];
    float r20=rot[6], r21=rot[7], r22=rot[8];
    float nx = n0*r00 + n1*r10 + n2*r20;
    float ny = n0*r01 + n1*r11 + n2*r21;
    float nz = n0*r02 + n1*r12 + n2*r22;
    float Y1 = -A1C1*ny;
    float Y2 =  A1C1*nz;
    float Y3 = -A1C1*nx;
    float Y4 =  A2C2*nx*ny;
    float Y5 = -A2C2*ny*nz;
    float Y6 =  Y6C*(3.f*nz*nz - 1.f);
    float Y7 = -A2C2*nx*nz;
    float Y8 =  Y8C*(nx*nx - ny*ny);
    const float* g = gAll + b*27;
    float L[3];
    #pragma unroll
    for (int c = 0; c < 3; ++c) {
      const float* gc = g + c*9;
      L[c] = A0C0*gc[0] + Y1*gc[1] + Y2*gc[2] + Y3*gc[3] + Y4*gc[4]
           + Y5*gc[5] + Y6*gc[6] + Y7*gc[7] + Y8*gc[8];
    }
    float4 fsv = *(const float4*)(fs4 + (size_t)b*V4 + (size_t)v*4);
    const float* tre = treAll + b*3;
    float o0 = fsv.x*r00 + fsv.y*r10 + fsv.z*r20 + tre[0];
    float o1 = fsv.x*r01 + fsv.y*r11 + fsv.z*r21 + tre[1];
    float o2 = fsv.x*r02 + fsv.y*r12 + fsv.z*r22 + tre[2];
    float* fst = out + FST_OFF + (size_t)b*M3 + (size_t)v*3;
    fst[0] = o0; fst[1] = o1; fst[2] = o2;
    float* fc = out + FC_OFF + (size_t)b*M3 + (size_t)v*3;
    fc[0] = fc[0]*L[0];
    fc[1] = fc[1]*L[1];
    fc[2] = fc[2]*L[2];
  } else {
    int idx = (bid - mainBlocks)*256 + threadIdx.x;
    if (idx >= NB*68) return;
    int b = idx / 68;
    int j = idx - b*68;
    int kp = keypoints[j];
    const float* rot = rotAll + b*9;
    const float* tre = treAll + b*3;
    float4 fsv = *(const float4*)(fs4 + (size_t)b*V4 + (size_t)kp*4);
    float o0 = fsv.x*rot[0] + fsv.y*rot[3] + fsv.z*rot[6] + tre[0];
    float o1 = fsv.x*rot[1] + fsv.y*rot[4] + fsv.z*rot[7] + tre[1];
    float o2 = fsv.x*rot[2] + fsv.y*rot[5] + fsv.z*rot[8] + tre[2];
    float zc = 10.0f - o2;
    float axv = 1015.0f*o0 + 112.0f*zc;
    float ayv = 1015.0f*o1 + 112.0f*zc;
    out[LM_OFF + (size_t)b*136 + (size_t)j*2 + 0] = axv/zc;
    out[LM_OFF + (size_t)b*136 + (size_t)j*2 + 1] = ayv/zc;
  }
}

// ======================= launch =======================
extern "C" void kernel_launch(void* const* d_in, const int* in_sizes, int n_in,
                              void* d_out, int out_size, void* d_ws, size_t ws_size,
                              hipStream_t stream) {
  const float* coeff     = (const float*)d_in[0];
  const float* idB       = (const float*)d_in[1];
  const float* exB       = (const float*)d_in[2];
  const float* texB      = (const float*)d_in[3];
  const float* meanshape = (const float*)d_in[4];
  const float* meantex   = (const float*)d_in[5];
  const int*   face_buf  = (const int*)d_in[6];
  const int*   point_buf = (const int*)d_in[7];
  const int*   keypoints = (const int*)d_in[8];
  float* out = (float*)d_out;
  float* ws  = (float*)d_ws;

  hipMemsetAsync((char*)d_ws + WS_MEAN*sizeof(float), 0, 3*sizeof(float), stream);

  hipLaunchKernelGGL(face3d_stageA1, dim3(56), dim3(256), 0, stream, meanshape, ws);
  hipLaunchKernelGGL(face3d_stageA2, dim3(1), dim3(256), 0, stream, coeff, ws);

  int rbB = (M3 + 511)/512;   // 210
  hipLaunchKernelGGL(face3d_stageB, dim3(rbB*4), dim3(256), 0, stream,
                     idB, exB, texB, meanshape, meantex,
                     ws + WS_CPAD, ws + WS_FS4, out + FC_OFF);

  hipLaunchKernelGGL(face3d_stageC, dim3(NB*CBLK), dim3(256), 0, stream,
                     face_buf, ws + WS_FS4, ws + WS_FN4);

  int mainBlocks = NB*DBLK;                 // 4480
  int lmBlocks   = (NB*68 + 255)/256;       // 9
  hipLaunchKernelGGL(face3d_stageD, dim3(mainBlocks + lmBlocks), dim3(256), 0, stream,
                     point_buf, keypoints, ws + WS_FS4, ws + WS_FN4,
                     ws + WS_ROT, ws + WS_TRE, ws + WS_G, out);
}

// Round 3
// 290.073 us; speedup vs baseline: 2.1957x; 2.1957x over previous
//
#include <hip/hip_runtime.h>

#define N_VERT 35709
#define N_FACE 70789
#define NB 32
#define M3 (3*N_VERT)        // 107127

// ---- workspace layout (float offsets), vertex-major batch-inner ----
#define WS_FS4X  ((size_t)0)                          // [N_VERT][32][4]
#define WS_FN4X  (WS_FS4X + (size_t)N_VERT*128)       // [N_FACE+1][32][4] (zero row at N_FACE)
#define WS_CPAD  (WS_FN4X + (size_t)(N_FACE+1)*128)   // [32][256]
#define WS_ROT   (WS_CPAD + (size_t)NB*256)           // [32][9]
#define WS_TRE   (WS_ROT + (size_t)NB*9)              // [32][3]
#define WS_G     (WS_TRE + (size_t)NB*3)              // [32][27]
#define WS_MEAN  (WS_G + (size_t)NB*27)               // [3] atomic sums

// ---- output layout (float offsets) ----
#define FC_OFF   ((size_t)0)
#define LM_OFF   ((size_t)NB*M3)                      // 3428064
#define FST_OFF  (LM_OFF + (size_t)NB*68*2)

// ---- SH constants ----
#define A0C0 0.88622692545275801f
#define A1C1 1.77245385090551603f
#define A2C2 2.42703239430f
#define Y6C  0.70062393935f
#define Y8C  1.21351619715f

// ======================= Stage A1: meanshape partial sums =======================
__global__ void __launch_bounds__(256) face3d_stageA1(
    const float* __restrict__ ms, float* __restrict__ ws) {
  float s0=0.f, s1=0.f, s2=0.f;
  for (int v = blockIdx.x*256 + threadIdx.x; v < N_VERT; v += gridDim.x*256) {
    s0 += ms[3*v+0]; s1 += ms[3*v+1]; s2 += ms[3*v+2];
  }
  #pragma unroll
  for (int off = 32; off > 0; off >>= 1) {
    s0 += __shfl_down(s0, off);
    s1 += __shfl_down(s1, off);
    s2 += __shfl_down(s2, off);
  }
  if ((threadIdx.x & 63) == 0) {
    atomicAdd(&ws[WS_MEAN+0], s0);
    atomicAdd(&ws[WS_MEAN+1], s1);
    atomicAdd(&ws[WS_MEAN+2], s2);
  }
}

// ======================= Stage A2: per-batch constants =======================
__global__ void __launch_bounds__(256) face3d_stageA2(
    const float* __restrict__ coeff, float* __restrict__ ws) {
  int t = threadIdx.x;
  float m0 = ws[WS_MEAN+0]*(1.0f/N_VERT);
  float m1 = ws[WS_MEAN+1]*(1.0f/N_VERT);
  float m2 = ws[WS_MEAN+2]*(1.0f/N_VERT);
  for (int idx = t; idx < NB*256; idx += 256) {
    int b = idx >> 8, k = idx & 255;
    ws[WS_CPAD + idx] = (k < 244) ? coeff[b*277 + k] : 0.0f;
  }
  for (int idx = t; idx < NB*27; idx += 256) {
    int b = idx / 27, k = idx - b*27;
    ws[WS_G + idx] = coeff[b*277 + 247 + k] + (((k % 9) == 0) ? 0.8f : 0.0f);
  }
  if (t < NB) {
    int b = t;
    float ax = coeff[b*277+244], ay = coeff[b*277+245], az = coeff[b*277+246];
    float cx=cosf(ax), sx=sinf(ax);
    float cy=cosf(ay), sy=sinf(ay);
    float cz=cosf(az), sz=sinf(az);
    float T00=cz*cy, T01=-sz, T02=cz*sy;
    float T10=sz*cy, T11=cz,  T12=sz*sy;
    float T20=-sy,   T21=0.f, T22=cy;
    float R[3][3];
    R[0][0]=T00; R[0][1]=T01*cx+T02*sx; R[0][2]=-T01*sx+T02*cx;
    R[1][0]=T10; R[1][1]=T11*cx+T12*sx; R[1][2]=-T11*sx+T12*cx;
    R[2][0]=T20; R[2][1]=T21*cx+T22*sx; R[2][2]=-T21*sx+T22*cx;
    float rot[3][3];
    #pragma unroll
    for (int c=0;c<3;c++)
      #pragma unroll
      for (int j=0;j<3;j++)
        rot[c][j] = R[j][c];
    #pragma unroll
    for (int c=0;c<3;c++)
      #pragma unroll
      for (int j=0;j<3;j++)
        ws[WS_ROT + b*9 + c*3 + j] = rot[c][j];
    #pragma unroll
    for (int j=0;j<3;j++)
      ws[WS_TRE + b*3 + j] = coeff[b*277+274+j]
        - (m0*rot[0][j] + m1*rot[1][j] + m2*rot[2][j]);
  }
}

// ======================= Stage B: GEMMs (1 row x 32 batches / thread) =======================
template<int NK4, int COFF>
__device__ __forceinline__ void phaseK(const float* __restrict__ Arow,
                                       const float4* __restrict__ Wl,
                                       float* __restrict__ acc) {
  const float4* __restrict__ A = (const float4*)Arow;
  float4 cur = A[0];
  #pragma unroll 1
  for (int s = 0; s < NK4; ++s) {
    float4 a = cur;
    if (s + 1 < NK4) cur = A[s+1];
    #pragma unroll
    for (int b = 0; b < NB; ++b) {
      float4 w = Wl[b*64 + COFF + s];
      acc[b] = fmaf(a.x, w.x, fmaf(a.y, w.y, fmaf(a.z, w.z, fmaf(a.w, w.w, acc[b]))));
    }
  }
}

__global__ void __launch_bounds__(256) face3d_stageB(
    const float* __restrict__ idB, const float* __restrict__ exB,
    const float* __restrict__ texB, const float* __restrict__ meanshape,
    const float* __restrict__ meantex, const float* __restrict__ cpad,
    float* __restrict__ fs4x, float* __restrict__ texOut) {
  __shared__ float4 W[2048];    // [32 b][64 k4] = 32 KB, whole coeff matrix
  int t = threadIdx.x;
  {
    const float4* __restrict__ src = (const float4*)cpad;
    #pragma unroll
    for (int j = 0; j < 8; ++j) W[t + 256*j] = src[t + 256*j];
  }
  __syncthreads();
  int r = blockIdx.x*256 + t;
  if (r >= M3) return;

  float acc[NB];
  #pragma unroll
  for (int b=0;b<NB;b++) acc[b]=0.f;
  phaseK<20, 0 >(idB + (size_t)r*80,  W, acc);   // id: K=80
  phaseK<16, 20>(exB + (size_t)r*64,  W, acc);   // ex: K=64
  {
    float ms = meanshape[r];
    int v = r/3, c = r - 3*v;
    float* dst = fs4x + (size_t)v*128 + c;
    #pragma unroll
    for (int b=0;b<NB;b++) dst[b*4] = acc[b] + ms;
  }
  #pragma unroll
  for (int b=0;b<NB;b++) acc[b]=0.f;
  phaseK<25, 36>(texB + (size_t)r*100, W, acc);  // tex: K=100
  {
    float mt = meantex[r];
    #pragma unroll
    for (int b=0;b<NB;b++) texOut[(size_t)b*M3 + r] = acc[b] + mt;  // coalesced per b
  }
}

// ======================= Stage C: face normals (8 faces x 32 batches / block) =======================
__global__ void __launch_bounds__(256) face3d_stageC(
    const int* __restrict__ face_buf, const float* __restrict__ fs4x,
    float* __restrict__ fn4x) {
  int t = threadIdx.x;
  int b = t & 31, fi = t >> 5;
  int f = blockIdx.x*8 + fi;
  if (f > N_FACE) return;
  float4* o = (float4*)(fn4x + ((size_t)f*32 + b)*4);
  if (f == N_FACE) { *o = make_float4(0.f,0.f,0.f,0.f); return; }
  int i0 = face_buf[f*3+0];
  int i1 = face_buf[f*3+1];
  int i2 = face_buf[f*3+2];
  float4 p1 = *(const float4*)(fs4x + ((size_t)i0*32 + b)*4);
  float4 p2 = *(const float4*)(fs4x + ((size_t)i1*32 + b)*4);
  float4 p3 = *(const float4*)(fs4x + ((size_t)i2*32 + b)*4);
  float e1x = p1.x-p2.x, e1y = p1.y-p2.y, e1z = p1.z-p2.z;
  float e2x = p2.x-p3.x, e2y = p2.y-p3.y, e2z = p2.z-p3.z;
  float nx = e1y*e2z - e1z*e2y;
  float ny = e1z*e2x - e1x*e2z;
  float nz = e1x*e2y - e1y*e2x;
  float inv = 1.0f / fmaxf(sqrtf(nx*nx + ny*ny + nz*nz), 1e-12f);
  *o = make_float4(nx*inv, ny*inv, nz*inv, 0.f);
}

// ======================= Stage D: vertex normals + lighting + fst (+landmarks) =======================
__global__ void __launch_bounds__(256) face3d_stageD(
    const int* __restrict__ point_buf, const int* __restrict__ keypoints,
    const float* __restrict__ fs4x, const float* __restrict__ fn4x,
    const float* __restrict__ rotAll, const float* __restrict__ treAll,
    const float* __restrict__ gAll, float* __restrict__ out) {
  const int mainBlocks = (N_VERT + 7)/8;   // 4464
  int bid = blockIdx.x;
  int t = threadIdx.x;
  if (bid < mainBlocks) {
    __shared__ float rotL[NB*9];
    __shared__ float treL[NB*3];
    __shared__ float gL[NB*27];
    __shared__ float fstL[NB*33];   // [b]: stride 33, [w*4+c]
    __shared__ float LL[NB*33];
    if (t < NB*9)  rotL[t] = rotAll[t];
    if (t < NB*3)  treL[t] = treAll[t];
    for (int i = t; i < NB*27; i += 256) gL[i] = gAll[i];
    __syncthreads();
    int b = t & 31, vi = t >> 5;
    int v0 = bid*8;
    int v = v0 + vi;
    if (v < N_VERT) {
      const int4 pb0 = *(const int4*)(point_buf + (size_t)v*8);
      const int4 pb1 = *(const int4*)(point_buf + (size_t)v*8 + 4);
      float4 g0 = *(const float4*)(fn4x + ((size_t)pb0.x*32 + b)*4);
      float4 g1 = *(const float4*)(fn4x + ((size_t)pb0.y*32 + b)*4);
      float4 g2 = *(const float4*)(fn4x + ((size_t)pb0.z*32 + b)*4);
      float4 g3 = *(const float4*)(fn4x + ((size_t)pb0.w*32 + b)*4);
      float4 g4 = *(const float4*)(fn4x + ((size_t)pb1.x*32 + b)*4);
      float4 g5 = *(const float4*)(fn4x + ((size_t)pb1.y*32 + b)*4);
      float4 g6 = *(const float4*)(fn4x + ((size_t)pb1.z*32 + b)*4);
      float4 g7 = *(const float4*)(fn4x + ((size_t)pb1.w*32 + b)*4);
      float sx = ((g0.x+g1.x)+(g2.x+g3.x)) + ((g4.x+g5.x)+(g6.x+g7.x));
      float sy = ((g0.y+g1.y)+(g2.y+g3.y)) + ((g4.y+g5.y)+(g6.y+g7.y));
      float sz = ((g0.z+g1.z)+(g2.z+g3.z)) + ((g4.z+g5.z)+(g6.z+g7.z));
      float inv = 1.0f / fmaxf(sqrtf(sx*sx + sy*sy + sz*sz), 1e-12f);
      float n0 = sx*inv, n1 = sy*inv, n2 = sz*inv;
      const float* rot = rotL + b*9;
      float r00=rot[0], r01=rot[1], r02=rot[2];
      float r10=rot[3], r11=rot[4], r12=rot[5];
      float r20=rot[6], r21=rot[7], r22=rot[8];
      float nx = n0*r00 + n1*r10 + n2*r20;
      float ny = n0*r01 + n1*r11 + n2*r21;
      float nz = n0*r02 + n1*r12 + n2*r22;
      float Y1 = -A1C1*ny;
      float Y2 =  A1C1*nz;
      float Y3 = -A1C1*nx;
      float Y4 =  A2C2*nx*ny;
      float Y5 = -A2C2*ny*nz;
      float Y6 =  Y6C*(3.f*nz*nz - 1.f);
      float Y7 = -A2C2*nx*nz;
      float Y8 =  Y8C*(nx*nx - ny*ny);
      const float* g = gL + b*27;
      #pragma unroll
      for (int c = 0; c < 3; ++c) {
        const float* gc = g + c*9;
        float Lc = A0C0*gc[0] + Y1*gc[1] + Y2*gc[2] + Y3*gc[3] + Y4*gc[4]
                 + Y5*gc[5] + Y6*gc[6] + Y7*gc[7] + Y8*gc[8];
        LL[b*33 + vi*4 + c] = Lc;
      }
      float4 fsv = *(const float4*)(fs4x + ((size_t)v*32 + b)*4);
      const float* tre = treL + b*3;
      fstL[b*33 + vi*4 + 0] = fsv.x*r00 + fsv.y*r10 + fsv.z*r20 + tre[0];
      fstL[b*33 + vi*4 + 1] = fsv.x*r01 + fsv.y*r11 + fsv.z*r21 + tre[1];
      fstL[b*33 + vi*4 + 2] = fsv.x*r02 + fsv.y*r12 + fsv.z*r22 + tre[2];
    }
    __syncthreads();
    // phase 2: transpose out. t -> b2 = t>>3 (32), w = t&7 (8 vertices)
    int b2 = t >> 3, w = t & 7;
    if (v0 + w < N_VERT) {
      size_t obase = (size_t)b2*M3 + (size_t)(v0 + w)*3;
      float f0 = fstL[b2*33 + w*4 + 0];
      float f1 = fstL[b2*33 + w*4 + 1];
      float f2 = fstL[b2*33 + w*4 + 2];
      out[FST_OFF + obase + 0] = f0;
      out[FST_OFF + obase + 1] = f1;
      out[FST_OFF + obase + 2] = f2;
      float l0 = LL[b2*33 + w*4 + 0];
      float l1 = LL[b2*33 + w*4 + 1];
      float l2 = LL[b2*33 + w*4 + 2];
      float t0 = out[FC_OFF + obase + 0];
      float t1 = out[FC_OFF + obase + 1];
      float t2 = out[FC_OFF + obase + 2];
      out[FC_OFF + obase + 0] = t0*l0;
      out[FC_OFF + obase + 1] = t1*l1;
      out[FC_OFF + obase + 2] = t2*l2;
    }
  } else {
    int idx = (bid - mainBlocks)*256 + t;
    if (idx >= NB*68) return;
    int b = idx & 31, j = idx >> 5;
    int kp = keypoints[j];
    const float* rot = rotAll + b*9;
    const float* tre = treAll + b*3;
    float4 fsv = *(const float4*)(fs4x + ((size_t)kp*32 + b)*4);
    float o0 = fsv.x*rot[0] + fsv.y*rot[3] + fsv.z*rot[6] + tre[0];
    float o1 = fsv.x*rot[1] + fsv.y*rot[4] + fsv.z*rot[7] + tre[1];
    float o2 = fsv.x*rot[2] + fsv.y*rot[5] + fsv.z*rot[8] + tre[2];
    float zc = 10.0f - o2;
    float axv = 1015.0f*o0 + 112.0f*zc;
    float ayv = 1015.0f*o1 + 112.0f*zc;
    out[LM_OFF + (size_t)b*136 + (size_t)j*2 + 0] = axv/zc;
    out[LM_OFF + (size_t)b*136 + (size_t)j*2 + 1] = ayv/zc;
  }
}

// ======================= launch =======================
extern "C" void kernel_launch(void* const* d_in, const int* in_sizes, int n_in,
                              void* d_out, int out_size, void* d_ws, size_t ws_size,
                              hipStream_t stream) {
  const float* coeff     = (const float*)d_in[0];
  const float* idB       = (const float*)d_in[1];
  const float* exB       = (const float*)d_in[2];
  const float* texB      = (const float*)d_in[3];
  const float* meanshape = (const float*)d_in[4];
  const float* meantex   = (const float*)d_in[5];
  const int*   face_buf  = (const int*)d_in[6];
  const int*   point_buf = (const int*)d_in[7];
  const int*   keypoints = (const int*)d_in[8];
  float* out = (float*)d_out;
  float* ws  = (float*)d_ws;

  hipMemsetAsync((char*)d_ws + WS_MEAN*sizeof(float), 0, 3*sizeof(float), stream);

  hipLaunchKernelGGL(face3d_stageA1, dim3(56), dim3(256), 0, stream, meanshape, ws);
  hipLaunchKernelGGL(face3d_stageA2, dim3(1), dim3(256), 0, stream, coeff, ws);

  int gridB = (M3 + 255)/256;            // 419
  hipLaunchKernelGGL(face3d_stageB, dim3(gridB), dim3(256), 0, stream,
                     idB, exB, texB, meanshape, meantex,
                     ws + WS_CPAD, ws + WS_FS4X, out + FC_OFF);

  int gridC = (N_FACE + 1 + 7)/8;        // 8849
  hipLaunchKernelGGL(face3d_stageC, dim3(gridC), dim3(256), 0, stream,
                     face_buf, ws + WS_FS4X, ws + WS_FN4X);

  int mainBlocks = (N_VERT + 7)/8;       // 4464
  int lmBlocks   = (NB*68 + 255)/256;    // 9
  hipLaunchKernelGGL(face3d_stageD, dim3(mainBlocks + lmBlocks), dim3(256), 0, stream,
                     point_buf, keypoints, ws + WS_FS4X, ws + WS_FN4X,
                     ws + WS_ROT, ws + WS_TRE, ws + WS_G, out);
}